// Round 13
// baseline (608.181 us; speedup 1.0000x reference)
//
#include <hip/hip_runtime.h>

#define LNUM 8
#define WD 128
#define BATCH 262144

typedef unsigned int u32;
typedef __attribute__((ext_vector_type(8))) short bf16x8;
typedef __attribute__((ext_vector_type(4))) float f32x4;

// packed f32x2 -> bf16x2 (single VALU op; validated R4+)
__device__ __forceinline__ u32 pk2(float x, float y){
  u32 r;
  asm("v_cvt_pk_bf16_f32 %0, %1, %2" : "=v"(r) : "v"(x), "v"(y));
  return r;
}

// NATURAL-order W image (mid1 k-map). Row-major bf16, XOR-swizzled 4-dword.
// 256 threads: row j=t>>1, half h=t&1. Validated R2+.
__device__ __forceinline__ void stage_Wnat(const float* __restrict__ src, u32* dst, int tid){
  const int j = tid >> 1, h = tid & 1;
  const float* s = src + j * WD + h * 64;
  u32* drow = dst + j * 64;
  const int base = h * 32;
  const u32 sz = (u32)((j & 7) << 2);
#pragma unroll
  for(int c = 0; c < 8; ++c){
    float4 f0 = *(const float4*)(s + c * 8);
    float4 f1 = *(const float4*)(s + c * 8 + 4);
    uint4 w;
    w.x = pk2(f0.x, f0.y); w.y = pk2(f0.z, f0.w);
    w.z = pk2(f1.x, f1.y); w.w = pk2(f1.z, f1.w);
    *(uint4*)(drow + (((u32)(base + c * 4)) ^ sz)) = w;
  }
}

// PERMUTED fragment-contiguous W image (mid2 k-map
// slot(lg,e) <-> k = kt*32+(e>>2)*16+lg*4+(e&3)): A-fragment for (lg,kt) is
// ONE b128 at dword (kt*16+lg*4)^sz. Validated R9+.
__device__ __forceinline__ void stage_Wperm(const float* __restrict__ src, u32* dst, int tid){
  const int j = tid >> 1, h = tid & 1;
  const float* srow = src + j * WD;
  u32* drow = dst + j * 64;
  const u32 sz = (u32)((j & 7) << 2);
#pragma unroll
  for(int kk = 0; kk < 2; ++kk){
    const int kt = 2 * h + kk;
#pragma unroll
    for(int g = 0; g < 4; ++g){
      float4 f0 = *(const float4*)(srow + kt * 32 + g * 4);
      float4 f1 = *(const float4*)(srow + kt * 32 + 16 + g * 4);
      uint4 w;
      w.x = pk2(f0.x, f0.y); w.y = pk2(f0.z, f0.w);
      w.z = pk2(f1.x, f1.y); w.w = pk2(f1.z, f1.w);
      *(uint4*)(drow + (((u32)(kt * 16 + g * 4)) ^ sz)) = w;
    }
  }
}

// DMA a 16384-dword two-matrix slab into LDS, 16 waves (BLK=1024).
__device__ __forceinline__ void stage_dma16(const u32* __restrict__ g, u32* l, int wv, int lane){
#pragma unroll
  for(int it = 0; it < 4; ++it){
    const int o = wv * 1024 + it * 256;
    __builtin_amdgcn_global_load_lds(
        (const __attribute__((address_space(1))) u32*)(g + o + lane * 4),
        (__attribute__((address_space(3))) u32*)(l + o),
        16, 0, 0);
  }
}
// Same, 4 waves (fallback BLK=256).
__device__ __forceinline__ void stage_dma4(const u32* __restrict__ g, u32* l, int wv, int lane){
#pragma unroll
  for(int it = 0; it < 16; ++it){
    const int o = wv * 4096 + it * 256;
    __builtin_amdgcn_global_load_lds(
        (const __attribute__((address_space(1))) u32*)(g + o + lane * 4),
        (__attribute__((address_space(3))) u32*)(l + o),
        16, 0, 0);
  }
}

// ---- stage-1 B-fragment pack ----
#define PACK_ST(dstv, uv) do { \
    uint4 pk_; \
    pk_.x = pk2(fmaxf(fmaf(uv, w1a_.x, g1a_.x), 0.f), fmaxf(fmaf(uv, w1a_.y, g1a_.y), 0.f)); \
    pk_.y = pk2(fmaxf(fmaf(uv, w1a_.z, g1a_.z), 0.f), fmaxf(fmaf(uv, w1a_.w, g1a_.w), 0.f)); \
    pk_.z = pk2(fmaxf(fmaf(uv, w1b_.x, g1b_.x), 0.f), fmaxf(fmaf(uv, w1b_.y, g1b_.y), 0.f)); \
    pk_.w = pk2(fmaxf(fmaf(uv, w1b_.z, g1b_.z), 0.f), fmaxf(fmaf(uv, w1b_.w, g1b_.w), 0.f)); \
    dstv = __builtin_bit_cast(bf16x8, pk_); \
  } while(0)

// ---- stage-4 fold of one finished mid2 j-tile (2 sample-subtiles) ----
#define FOLD2(jtc) do { \
    const float4 wc_ = *(const float4*)(W4 + (jtc) * 16 + lg * 4); \
    p0 = fmaf(fmaxf(aa[(jtc)&1][0][0], 0.f), wc_.x, p0); \
    p0 = fmaf(fmaxf(aa[(jtc)&1][0][1], 0.f), wc_.y, p0); \
    p0 = fmaf(fmaxf(aa[(jtc)&1][0][2], 0.f), wc_.z, p0); \
    p0 = fmaf(fmaxf(aa[(jtc)&1][0][3], 0.f), wc_.w, p0); \
    p1 = fmaf(fmaxf(aa[(jtc)&1][1][0], 0.f), wc_.x, p1); \
    p1 = fmaf(fmaxf(aa[(jtc)&1][1][1], 0.f), wc_.y, p1); \
    p1 = fmaf(fmaxf(aa[(jtc)&1][1][2], 0.f), wc_.z, p1); \
    p1 = fmaf(fmaxf(aa[(jtc)&1][1][3], 0.f), wc_.w, p1); \
  } while(0)

// 4-stage MLP for ONE WAVE'S 32 SAMPLES (halved state for 4 waves/SIMD).
// Same per-sample math/k-maps as R10-R12 (absmax-validated): mid1 natural
// k-map (A=b128 natural LDS, C-init=b2), mid2 permuted k-map (B = lane's OWN
// trq dwords, A=b128 fragment-contiguous LDS, C-init=b3).
// jt-blocked mid1 caps acc at 32 regs. Valid pre on all lanes; samples are
// lm (p0) and 16+lm (p1): owner lane s<32 uses (lane&16 ? p1 : p0).
__device__ __forceinline__ float mlp32(
    float u, const u32* __restrict__ W2lds, const u32* __restrict__ W3lds,
    const float* __restrict__ W1, const float* __restrict__ b1,
    const float* __restrict__ b2, const float* __restrict__ b3,
    const float* __restrict__ W4, int lm, int lg, int lane)
{
  const float us0 = __shfl(u, lm, 64);
  const float us1 = __shfl(u, 16 + lm, 64);

  // ---- stage1: pack bv[4][2] (32 regs, live through mid1) ----
  bf16x8 bv[4][2];
#pragma unroll
  for(int kt = 0; kt < 4; ++kt){
    const int ko_ = kt * 32 + lg * 8;
    const float4 w1a_ = *(const float4*)(W1 + ko_);
    const float4 w1b_ = *(const float4*)(W1 + ko_ + 4);
    const float4 g1a_ = *(const float4*)(b1 + ko_);
    const float4 g1b_ = *(const float4*)(b1 + ko_ + 4);
    PACK_ST(bv[kt][0], us0);
    PACK_ST(bv[kt][1], us1);
  }

  // ---- mid1, jt-blocked (acc 32 regs); pack into mid2 B-operand trq ----
  uint4 trq[4][2];
#pragma unroll
  for(int jb = 0; jb < 2; ++jb){
    f32x4 acc[4][2];
#pragma unroll
    for(int q = 0; q < 4; ++q){
      const float4 bb = *(const float4*)(b2 + (jb * 4 + q) * 16 + lg * 4);
      const f32x4 bi = {bb.x, bb.y, bb.z, bb.w};
      acc[q][0] = bi; acc[q][1] = bi;
    }
    __builtin_amdgcn_s_setprio(1);
#pragma unroll
    for(int kt = 0; kt < 4; ++kt){
      const u32 kdw = (u32)(kt * 16 + lg * 4);
#pragma unroll
      for(int q = 0; q < 4; ++q){
        const int j = lm + 16 * (jb * 4 + q);
        bf16x8 av = __builtin_bit_cast(bf16x8,
            *(const uint4*)(W2lds + j * 64 + (kdw ^ (u32)((j & 7) << 2))));
        acc[q][0] = __builtin_amdgcn_mfma_f32_16x16x32_bf16(av, bv[kt][0], acc[q][0], 0, 0, 0);
        acc[q][1] = __builtin_amdgcn_mfma_f32_16x16x32_bf16(av, bv[kt][1], acc[q][1], 0, 0, 0);
      }
    }
    __builtin_amdgcn_s_setprio(0);
#pragma unroll
    for(int q = 0; q < 4; ++q){
      const int jt = jb * 4 + q;
#pragma unroll
      for(int st = 0; st < 2; ++st){
        const u32 d0 = pk2(fmaxf(acc[q][st][0], 0.f), fmaxf(acc[q][st][1], 0.f));
        const u32 d1 = pk2(fmaxf(acc[q][st][2], 0.f), fmaxf(acc[q][st][3], 0.f));
        if(jt & 1){ trq[jt >> 1][st].z = d0; trq[jt >> 1][st].w = d1; }
        else      { trq[jt >> 1][st].x = d0; trq[jt >> 1][st].y = d1; }
      }
    }
  }

  // ---- mid2 + stage-4 fold (pipelined one tile deep) ----
  f32x4 aa[2][2];
  float p0 = 0.f, p1 = 0.f;
#pragma unroll
  for(int jt = 0; jt < 8; ++jt){
    const int j = lm + 16 * jt;
    const u32 sz = (u32)((j & 7) << 2);
    const u32* r = W3lds + j * 64;
    bf16x8 av[4];
#pragma unroll
    for(int kt = 0; kt < 4; ++kt)
      av[kt] = __builtin_bit_cast(bf16x8,
          *(const uint4*)(r + (((u32)(kt * 16 + lg * 4)) ^ sz)));
    const float4 bc = *(const float4*)(b3 + jt * 16 + lg * 4);
    const f32x4 ci = {bc.x, bc.y, bc.z, bc.w};
    aa[jt & 1][0] = ci; aa[jt & 1][1] = ci;
    if(jt > 0) FOLD2(jt - 1);
    __builtin_amdgcn_s_setprio(1);
#pragma unroll
    for(int kt = 0; kt < 4; ++kt){
      aa[jt & 1][0] = __builtin_amdgcn_mfma_f32_16x16x32_bf16(
          av[kt], __builtin_bit_cast(bf16x8, trq[kt][0]), aa[jt & 1][0], 0, 0, 0);
      aa[jt & 1][1] = __builtin_amdgcn_mfma_f32_16x16x32_bf16(
          av[kt], __builtin_bit_cast(bf16x8, trq[kt][1]), aa[jt & 1][1], 0, 0, 0);
    }
    __builtin_amdgcn_s_setprio(0);
  }
  FOLD2(7);

  p0 += __shfl_xor(p0, 16, 64); p0 += __shfl_xor(p0, 32, 64);
  p1 += __shfl_xor(p1, 16, 64); p1 += __shfl_xor(p1, 32, 64);
  return (lane & 16) ? p1 : p0;
}

// ---------------- preprocess: fp32 weights -> bf16 LDS-image in d_ws ----------------
extern "C" __global__ void __launch_bounds__(256)
prep_kernel(const float* __restrict__ sW2, const float* __restrict__ sW3,
            const float* __restrict__ tW2, const float* __restrict__ tW3,
            u32* __restrict__ ws)
{
  const int b = blockIdx.x;
  const int layer = b >> 2, which = b & 3;
  const float* src = (which == 0 ? sW2 : which == 1 ? sW3 : which == 2 ? tW2 : tW3)
                     + layer * (WD * WD);
  u32* dst = ws + b * 8192;
  if(which & 1) stage_Wperm(src, dst, threadIdx.x);
  else          stage_Wnat (src, dst, threadIdx.x);
}

// ---------------- main: 1024 threads, 16 waves x 32 samples, DMA dbuf ----------------
extern "C" __global__ void __launch_bounds__(1024)
flow_dma(const float* __restrict__ x, const float* __restrict__ s_scale,
         const float* __restrict__ sW1, const float* __restrict__ sb1,
         const float* __restrict__ sb2, const float* __restrict__ sb3,
         const float* __restrict__ sW4, const float* __restrict__ sb4,
         const float* __restrict__ tW1, const float* __restrict__ tb1,
         const float* __restrict__ tb2, const float* __restrict__ tb3,
         const float* __restrict__ tW4, const float* __restrict__ tb4,
         const u32* __restrict__ wimg, float* __restrict__ out)
{
  __shared__ u32 Wbuf[2][16384];   // 128 KB: [buf][W2(8192) | W3(8192)]

  const int tid = threadIdx.x;
  const int lane = tid & 63, lg = lane >> 4, lm = lane & 15, wv = tid >> 6;
  const int sBase = (int)blockIdx.x * 512 + wv * 32;   // wave's 32 samples
  const bool owner = (lane < 32);

  float2 ab = make_float2(0.f, 0.f);
  if(owner) ab = ((const float2*)x)[sBase + lane];
  float* scat = out + 2 * BATCH;
  float sv = 0.f;

  stage_dma16(wimg, Wbuf[0], wv, lane);

#pragma unroll 1
  for(int ph = 0; ph < 2 * LNUM; ++ph){
    const int i = ph >> 1, isT = ph & 1, parity = i & 1;
    asm volatile("s_waitcnt vmcnt(0)" ::: "memory");
    __syncthreads();
    if(ph < 2 * LNUM - 1)
      stage_dma16(wimg + (ph + 1) * 16384, Wbuf[(ph + 1) & 1], wv, lane);

    const int off = i * WD;
    const float u = parity ? ab.y : ab.x;
    const u32* W2l = Wbuf[ph & 1];
    const u32* W3l = Wbuf[ph & 1] + 8192;

    if(!isT){
      float pre = mlp32(u, W2l, W3l, sW1 + off, sb1 + off,
                        sb2 + off, sb3 + off, sW4 + off, lm, lg, lane) + sb4[i];
      sv = s_scale[i] * tanhf(pre);
      if(owner) scat[i * BATCH + sBase + lane] = sv;
    } else {
      float pre = mlp32(u, W2l, W3l, tW1 + off, tb1 + off,
                        tb2 + off, tb3 + off, tW4 + off, lm, lg, lane) + tb4[i];
      const float tv = tanhf(pre);
      const float e = expf(sv);
      if(parity) ab.x = e * ab.x + tv; else ab.y = e * ab.y + tv;
    }
  }

  if(owner) ((float2*)out)[sBase + lane] = ab;
}

// ---------------- fallback (ws too small): 256 thr, inline staging ----------------
extern "C" __global__ void __launch_bounds__(256)
flow_fb(const float* __restrict__ x, const float* __restrict__ s_scale,
        const float* __restrict__ sW1, const float* __restrict__ sb1,
        const float* __restrict__ sW2, const float* __restrict__ sb2,
        const float* __restrict__ sW3, const float* __restrict__ sb3,
        const float* __restrict__ sW4, const float* __restrict__ sb4,
        const float* __restrict__ tW1, const float* __restrict__ tb1,
        const float* __restrict__ tW2, const float* __restrict__ tb2,
        const float* __restrict__ tW3, const float* __restrict__ tb3,
        const float* __restrict__ tW4, const float* __restrict__ tb4,
        float* __restrict__ out)
{
  __shared__ u32 Wlds[2][8192];

  const int tid = threadIdx.x;
  const int lane = tid & 63, lg = lane >> 4, lm = lane & 15, wv = tid >> 6;
  const int sBase = (int)blockIdx.x * 128 + wv * 32;
  const bool owner = (lane < 32);

  float2 ab = make_float2(0.f, 0.f);
  if(owner) ab = ((const float2*)x)[sBase + lane];
  float* scat = out + 2 * BATCH;
  float sv = 0.f;

#pragma unroll 1
  for(int i = 0; i < LNUM; ++i){
    const int parity = i & 1;
    const int off = i * WD, offW = i * (WD * WD);

    __syncthreads();
    stage_Wnat (sW2 + offW, Wlds[0], tid);
    stage_Wperm(sW3 + offW, Wlds[1], tid);
    __syncthreads();
    const float u = parity ? ab.y : ab.x;
    float preS = mlp32(u, Wlds[0], Wlds[1], sW1 + off, sb1 + off,
                       sb2 + off, sb3 + off, sW4 + off, lm, lg, lane) + sb4[i];
    sv = s_scale[i] * tanhf(preS);
    if(owner) scat[i * BATCH + sBase + lane] = sv;

    __syncthreads();
    stage_Wnat (tW2 + offW, Wlds[0], tid);
    stage_Wperm(tW3 + offW, Wlds[1], tid);
    __syncthreads();
    float preT = mlp32(u, Wlds[0], Wlds[1], tW1 + off, tb1 + off,
                       tb2 + off, tb3 + off, tW4 + off, lm, lg, lane) + tb4[i];
    const float tv = tanhf(preT);
    const float e = expf(sv);
    if(parity) ab.x = e * ab.x + tv; else ab.y = e * ab.y + tv;
  }

  if(owner) ((float2*)out)[sBase + lane] = ab;
}

extern "C" void kernel_launch(void* const* d_in, const int* in_sizes, int n_in,
                              void* d_out, int out_size, void* d_ws, size_t ws_size,
                              hipStream_t stream) {
  (void)in_sizes; (void)n_in; (void)out_size;
  const float* p[18];
  for(int k = 0; k < 18; ++k) p[k] = (const float*)d_in[k];

  const size_t need = (size_t)32 * 8192 * 4;   // 1 MiB bf16 weight image
  if(ws_size >= need){
    u32* ws = (u32*)d_ws;
    hipLaunchKernelGGL(prep_kernel, dim3(32), dim3(256), 0, stream,
                       p[4], p[6], p[12], p[14], ws);
    hipLaunchKernelGGL(flow_dma, dim3(BATCH / 512), dim3(1024), 0, stream,
                       p[0], p[1], p[2], p[3], p[5], p[7], p[8], p[9],
                       p[10], p[11], p[13], p[15], p[16], p[17],
                       (const u32*)ws, (float*)d_out);
  } else {
    hipLaunchKernelGGL(flow_fb, dim3(BATCH / 128), dim3(256), 0, stream,
                       p[0], p[1], p[2], p[3], p[4], p[5], p[6], p[7], p[8], p[9],
                       p[10], p[11], p[12], p[13], p[14], p[15], p[16], p[17],
                       (float*)d_out);
  }
}

// Round 14
// 333.744 us; speedup vs baseline: 1.8223x; 1.8223x over previous
//
#include <hip/hip_runtime.h>

#define LNUM 8
#define WD 128
#define BATCH 262144

typedef unsigned int u32;
typedef __attribute__((ext_vector_type(8))) short bf16x8;
typedef __attribute__((ext_vector_type(4))) float f32x4;

#define MFMA __builtin_amdgcn_mfma_f32_16x16x32_bf16
#define BC8(x) __builtin_bit_cast(bf16x8, x)

// packed f32x2 -> bf16x2 (single VALU op; validated R4+)
__device__ __forceinline__ u32 pk2(float x, float y){
  u32 r;
  asm("v_cvt_pk_bf16_f32 %0, %1, %2" : "=v"(r) : "v"(x), "v"(y));
  return r;
}

// NATURAL-order W image (mid1 k-map). Row-major bf16, XOR-swizzled 4-dword.
// 256 threads: row j=t>>1, half h=t&1. Validated R2+.
__device__ __forceinline__ void stage_Wnat(const float* __restrict__ src, u32* dst, int tid){
  const int j = tid >> 1, h = tid & 1;
  const float* s = src + j * WD + h * 64;
  u32* drow = dst + j * 64;
  const int base = h * 32;
  const u32 sz = (u32)((j & 7) << 2);
#pragma unroll
  for(int c = 0; c < 8; ++c){
    float4 f0 = *(const float4*)(s + c * 8);
    float4 f1 = *(const float4*)(s + c * 8 + 4);
    uint4 w;
    w.x = pk2(f0.x, f0.y); w.y = pk2(f0.z, f0.w);
    w.z = pk2(f1.x, f1.y); w.w = pk2(f1.z, f1.w);
    *(uint4*)(drow + (((u32)(base + c * 4)) ^ sz)) = w;
  }
}

// PERMUTED fragment-contiguous W image (mid2 k-map
// slot(lg,e) <-> k = kt*32+(e>>2)*16+lg*4+(e&3)): A-fragment for (lg,kt) is
// ONE b128 at dword (kt*16+lg*4)^sz. Validated R9+.
__device__ __forceinline__ void stage_Wperm(const float* __restrict__ src, u32* dst, int tid){
  const int j = tid >> 1, h = tid & 1;
  const float* srow = src + j * WD;
  u32* drow = dst + j * 64;
  const u32 sz = (u32)((j & 7) << 2);
#pragma unroll
  for(int kk = 0; kk < 2; ++kk){
    const int kt = 2 * h + kk;
#pragma unroll
    for(int g = 0; g < 4; ++g){
      float4 f0 = *(const float4*)(srow + kt * 32 + g * 4);
      float4 f1 = *(const float4*)(srow + kt * 32 + 16 + g * 4);
      uint4 w;
      w.x = pk2(f0.x, f0.y); w.y = pk2(f0.z, f0.w);
      w.z = pk2(f1.x, f1.y); w.w = pk2(f1.z, f1.w);
      *(uint4*)(drow + (((u32)(kt * 16 + g * 4)) ^ sz)) = w;
    }
  }
}

// DMA a 16384-dword (two-matrix) slab into LDS, 8 waves (BLK=512). R11-proven.
__device__ __forceinline__ void stage_dma(const u32* __restrict__ g, u32* l, int wv, int lane){
#pragma unroll
  for(int it = 0; it < 8; ++it){
    const int o = wv * 2048 + it * 256;
    __builtin_amdgcn_global_load_lds(
        (const __attribute__((address_space(1))) u32*)(g + o + lane * 4),
        (__attribute__((address_space(3))) u32*)(l + o),
        16, 0, 0);
  }
}

struct TrQ { uint4 q[4][2]; };   // mid2 B-operands [kt][st] (validated R9-R13)

// stage-1: pack B-fragments for 32 samples (2 sample-subtiles)
__device__ __forceinline__ void pack_bv(float us0, float us1,
    const float* __restrict__ W1, const float* __restrict__ b1,
    int lg, bf16x8 (&bv)[4][2])
{
#pragma unroll
  for(int kt = 0; kt < 4; ++kt){
    const int ko = kt * 32 + lg * 8;
    const float4 w1a = *(const float4*)(W1 + ko);
    const float4 w1b = *(const float4*)(W1 + ko + 4);
    const float4 g1a = *(const float4*)(b1 + ko);
    const float4 g1b = *(const float4*)(b1 + ko + 4);
    uint4 pa, pb;
    pa.x = pk2(fmaxf(fmaf(us0, w1a.x, g1a.x), 0.f), fmaxf(fmaf(us0, w1a.y, g1a.y), 0.f));
    pa.y = pk2(fmaxf(fmaf(us0, w1a.z, g1a.z), 0.f), fmaxf(fmaf(us0, w1a.w, g1a.w), 0.f));
    pa.z = pk2(fmaxf(fmaf(us0, w1b.x, g1b.x), 0.f), fmaxf(fmaf(us0, w1b.y, g1b.y), 0.f));
    pa.w = pk2(fmaxf(fmaf(us0, w1b.z, g1b.z), 0.f), fmaxf(fmaf(us0, w1b.w, g1b.w), 0.f));
    pb.x = pk2(fmaxf(fmaf(us1, w1a.x, g1a.x), 0.f), fmaxf(fmaf(us1, w1a.y, g1a.y), 0.f));
    pb.y = pk2(fmaxf(fmaf(us1, w1a.z, g1a.z), 0.f), fmaxf(fmaf(us1, w1a.w, g1a.w), 0.f));
    pb.z = pk2(fmaxf(fmaf(us1, w1b.x, g1b.x), 0.f), fmaxf(fmaf(us1, w1b.y, g1b.y), 0.f));
    pb.w = pk2(fmaxf(fmaf(us1, w1b.z, g1b.z), 0.f), fmaxf(fmaf(us1, w1b.w, g1b.w), 0.f));
    bv[kt][0] = BC8(pa);
    bv[kt][1] = BC8(pb);
  }
}

// mid1 j-block (4 j-tiles x 2 sample-subtiles), natural k-map, C-init = bias
__device__ __forceinline__ void mid1_jb(const u32* __restrict__ W2lds,
    const float* __restrict__ b2, const bf16x8 (&bv)[4][2],
    int jb, int lm, int lg, f32x4 (&acc)[4][2])
{
#pragma unroll
  for(int q = 0; q < 4; ++q){
    const float4 bb = *(const float4*)(b2 + (jb * 4 + q) * 16 + lg * 4);
    const f32x4 bi = {bb.x, bb.y, bb.z, bb.w};
    acc[q][0] = bi; acc[q][1] = bi;
  }
  __builtin_amdgcn_s_setprio(1);
#pragma unroll
  for(int kt = 0; kt < 4; ++kt){
    const u32 kdw = (u32)(kt * 16 + lg * 4);
#pragma unroll
    for(int q = 0; q < 4; ++q){
      const int j = lm + 16 * (jb * 4 + q);
      bf16x8 av = BC8(*(const uint4*)(W2lds + j * 64 + (kdw ^ (u32)((j & 7) << 2))));
      acc[q][0] = MFMA(av, bv[kt][0], acc[q][0], 0, 0, 0);
      acc[q][1] = MFMA(av, bv[kt][1], acc[q][1], 0, 0, 0);
    }
  }
  __builtin_amdgcn_s_setprio(0);
}

// relu + pack one mid1 j-block into mid2 B-operand layout (validated R9+)
__device__ __forceinline__ void trans_jb(const f32x4 (&acc)[4][2], int jb, TrQ& tq){
#pragma unroll
  for(int q = 0; q < 4; ++q){
    const int jt = jb * 4 + q;
#pragma unroll
    for(int st = 0; st < 2; ++st){
      const u32 d0 = pk2(fmaxf(acc[q][st][0], 0.f), fmaxf(acc[q][st][1], 0.f));
      const u32 d1 = pk2(fmaxf(acc[q][st][2], 0.f), fmaxf(acc[q][st][3], 0.f));
      if(jt & 1){ tq.q[jt >> 1][st].z = d0; tq.q[jt >> 1][st].w = d1; }
      else      { tq.q[jt >> 1][st].x = d0; tq.q[jt >> 1][st].y = d1; }
    }
  }
}

// stage-4 fold of finished mid2 j-tile (2 sample-subtiles)
#define FOLDX(aaX, pa, pb, W4p, jtc) do { \
    const float4 wc_ = *(const float4*)((W4p) + (jtc) * 16 + lg * 4); \
    pa = fmaf(fmaxf(aaX[(jtc)&1][0][0], 0.f), wc_.x, pa); \
    pa = fmaf(fmaxf(aaX[(jtc)&1][0][1], 0.f), wc_.y, pa); \
    pa = fmaf(fmaxf(aaX[(jtc)&1][0][2], 0.f), wc_.z, pa); \
    pa = fmaf(fmaxf(aaX[(jtc)&1][0][3], 0.f), wc_.w, pa); \
    pb = fmaf(fmaxf(aaX[(jtc)&1][1][0], 0.f), wc_.x, pb); \
    pb = fmaf(fmaxf(aaX[(jtc)&1][1][1], 0.f), wc_.y, pb); \
    pb = fmaf(fmaxf(aaX[(jtc)&1][1][2], 0.f), wc_.z, pb); \
    pb = fmaf(fmaxf(aaX[(jtc)&1][1][3], 0.f), wc_.w, pb); \
  } while(0)

// one mid2 j-tile step (permuted k-map; B = own TrQ; fold pipelined 1 deep)
#define MID2_STEP(W3l, b3p, W4p, tq, aaX, pa, pb, jt) do { \
    const int j_ = lm + 16 * (jt); \
    const u32 sz_ = (u32)((j_ & 7) << 2); \
    const u32* r_ = (W3l) + j_ * 64; \
    bf16x8 av0_ = BC8(*(const uint4*)(r_ + (((u32)(lg * 4)) ^ sz_))); \
    bf16x8 av1_ = BC8(*(const uint4*)(r_ + (((u32)(16 + lg * 4)) ^ sz_))); \
    bf16x8 av2_ = BC8(*(const uint4*)(r_ + (((u32)(32 + lg * 4)) ^ sz_))); \
    bf16x8 av3_ = BC8(*(const uint4*)(r_ + (((u32)(48 + lg * 4)) ^ sz_))); \
    const float4 bc_ = *(const float4*)((b3p) + (jt) * 16 + lg * 4); \
    const f32x4 ci_ = {bc_.x, bc_.y, bc_.z, bc_.w}; \
    aaX[(jt)&1][0] = ci_; aaX[(jt)&1][1] = ci_; \
    if((jt) > 0) FOLDX(aaX, pa, pb, W4p, (jt) - 1); \
    __builtin_amdgcn_s_setprio(1); \
    aaX[(jt)&1][0] = MFMA(av0_, BC8(tq.q[0][0]), aaX[(jt)&1][0], 0, 0, 0); \
    aaX[(jt)&1][1] = MFMA(av0_, BC8(tq.q[0][1]), aaX[(jt)&1][1], 0, 0, 0); \
    aaX[(jt)&1][0] = MFMA(av1_, BC8(tq.q[1][0]), aaX[(jt)&1][0], 0, 0, 0); \
    aaX[(jt)&1][1] = MFMA(av1_, BC8(tq.q[1][1]), aaX[(jt)&1][1], 0, 0, 0); \
    aaX[(jt)&1][0] = MFMA(av2_, BC8(tq.q[2][0]), aaX[(jt)&1][0], 0, 0, 0); \
    aaX[(jt)&1][1] = MFMA(av2_, BC8(tq.q[2][1]), aaX[(jt)&1][1], 0, 0, 0); \
    aaX[(jt)&1][0] = MFMA(av3_, BC8(tq.q[3][0]), aaX[(jt)&1][0], 0, 0, 0); \
    aaX[(jt)&1][1] = MFMA(av3_, BC8(tq.q[3][1]), aaX[(jt)&1][1], 0, 0, 0); \
    __builtin_amdgcn_s_setprio(0); \
  } while(0)

// ---------------- preprocess: fp32 weights -> bf16 slab image in d_ws ----------------
// Slab 2i = {sW2_i | tW2_i} (natural), slab 2i+1 = {sW3_i | tW3_i} (permuted).
extern "C" __global__ void __launch_bounds__(256)
prep_kernel(const float* __restrict__ sW2, const float* __restrict__ sW3,
            const float* __restrict__ tW2, const float* __restrict__ tW3,
            u32* __restrict__ ws)
{
  const int b = blockIdx.x;                       // 32 = 8 layers x 4 matrices
  const int layer = b >> 2, which = b & 3;        // 0 sW2, 1 sW3, 2 tW2, 3 tW3
  const float* src = (which == 0 ? sW2 : which == 1 ? sW3 : which == 2 ? tW2 : tW3)
                     + layer * (WD * WD);
  u32* dst = ws + (size_t)(2 * layer + (which & 1)) * 16384 + (size_t)(which >> 1) * 8192;
  if(which & 1) stage_Wperm(src, dst, threadIdx.x);
  else          stage_Wnat (src, dst, threadIdx.x);
}

// ---------------- main: 512 thr, 8 waves x 32 samples, dual s||t pipelines ----------------
extern "C" __global__ void __launch_bounds__(512)
flow_dma(const float* __restrict__ x, const float* __restrict__ s_scale,
         const float* __restrict__ sW1, const float* __restrict__ sb1,
         const float* __restrict__ sb2, const float* __restrict__ sb3,
         const float* __restrict__ sW4, const float* __restrict__ sb4,
         const float* __restrict__ tW1, const float* __restrict__ tb1,
         const float* __restrict__ tb2, const float* __restrict__ tb3,
         const float* __restrict__ tW4, const float* __restrict__ tb4,
         const u32* __restrict__ wimg, float* __restrict__ out)
{
  __shared__ u32 Wbuf[2][16384];   // 128 KB: buf0 = {W2s|W2t}, buf1 = {W3s|W3t}

  const int tid = threadIdx.x;
  const int lane = tid & 63, lg = lane >> 4, lm = lane & 15, wv = tid >> 6;
  const int sBase = (int)blockIdx.x * 256 + wv * 32;   // wave's 32 samples
  const bool owner = (lane < 32);

  float2 ab = make_float2(0.f, 0.f);
  if(owner) ab = ((const float2*)x)[sBase + lane];
  float* scat = out + 2 * BATCH;

  stage_dma(wimg, Wbuf[0], wv, lane);                  // slab 0

#pragma unroll 1
  for(int i = 0; i < LNUM; ++i){
    const int parity = i & 1;
    const int off = i * WD;
    const float u = parity ? ab.y : ab.x;
    const float us0 = __shfl(u, lm, 64);
    const float us1 = __shfl(u, 16 + lm, 64);

    // ---- phase A: mid1_s || mid1_t (slab 2i in Wbuf[0]) ----
    asm volatile("s_waitcnt vmcnt(0)" ::: "memory");
    __syncthreads();
    stage_dma(wimg + (size_t)(2 * i + 1) * 16384, Wbuf[1], wv, lane);

    const u32* W2s = Wbuf[0];
    const u32* W2t = Wbuf[0] + 8192;

    bf16x8 bvs[4][2], bvt[4][2];
    f32x4 as0[4][2], as1[4][2], at0[4][2], at1[4][2];
    TrQ tqs, tqt;
    pack_bv(us0, us1, sW1 + off, sb1 + off, lg, bvs);
    mid1_jb(W2s, sb2 + off, bvs, 0, lm, lg, as0);
    pack_bv(us0, us1, tW1 + off, tb1 + off, lg, bvt);   // VALU under s-MFMAs
    mid1_jb(W2s, sb2 + off, bvs, 1, lm, lg, as1);
    mid1_jb(W2t, tb2 + off, bvt, 0, lm, lg, at0);
    trans_jb(as0, 0, tqs); trans_jb(as1, 1, tqs);       // VALU under t-MFMAs
    mid1_jb(W2t, tb2 + off, bvt, 1, lm, lg, at1);
    trans_jb(at0, 0, tqt); trans_jb(at1, 1, tqt);

    // ---- phase B: mid2_s || mid2_t + stage-4 (slab 2i+1 in Wbuf[1]) ----
    asm volatile("s_waitcnt vmcnt(0)" ::: "memory");
    __syncthreads();
    if(i < LNUM - 1)
      stage_dma(wimg + (size_t)(2 * i + 2) * 16384, Wbuf[0], wv, lane);

    const u32* W3s = Wbuf[1];
    const u32* W3t = Wbuf[1] + 8192;

    f32x4 aas[2][2], aat[2][2];
    float ps0 = 0.f, ps1 = 0.f, pt0 = 0.f, pt1 = 0.f;
#pragma unroll
    for(int jt = 0; jt < 8; ++jt){
      MID2_STEP(W3s, sb3 + off, sW4 + off, tqs, aas, ps0, ps1, jt);
      MID2_STEP(W3t, tb3 + off, tW4 + off, tqt, aat, pt0, pt1, jt);
    }
    FOLDX(aas, ps0, ps1, sW4 + off, 7);
    FOLDX(aat, pt0, pt1, tW4 + off, 7);

    ps0 += __shfl_xor(ps0, 16, 64); ps0 += __shfl_xor(ps0, 32, 64);
    ps1 += __shfl_xor(ps1, 16, 64); ps1 += __shfl_xor(ps1, 32, 64);
    pt0 += __shfl_xor(pt0, 16, 64); pt0 += __shfl_xor(pt0, 32, 64);
    pt1 += __shfl_xor(pt1, 16, 64); pt1 += __shfl_xor(pt1, 32, 64);
    const float pres = ((lane & 16) ? ps1 : ps0) + sb4[i];
    const float pret = ((lane & 16) ? pt1 : pt0) + tb4[i];
    const float sv = s_scale[i] * tanhf(pres);
    const float tv = tanhf(pret);
    if(owner) scat[i * BATCH + sBase + lane] = sv;
    const float e = expf(sv);
    if(parity) ab.x = e * ab.x + tv; else ab.y = e * ab.y + tv;
  }

  if(owner) ((float2*)out)[sBase + lane] = ab;
}

// ---------------- fallback (ws too small): 256 thr, inline staging, same math ----------------
extern "C" __global__ void __launch_bounds__(256)
flow_fb(const float* __restrict__ x, const float* __restrict__ s_scale,
        const float* __restrict__ sW1, const float* __restrict__ sb1,
        const float* __restrict__ sW2, const float* __restrict__ sb2,
        const float* __restrict__ sW3, const float* __restrict__ sb3,
        const float* __restrict__ sW4, const float* __restrict__ sb4,
        const float* __restrict__ tW1, const float* __restrict__ tb1,
        const float* __restrict__ tW2, const float* __restrict__ tb2,
        const float* __restrict__ tW3, const float* __restrict__ tb3,
        const float* __restrict__ tW4, const float* __restrict__ tb4,
        float* __restrict__ out)
{
  __shared__ u32 Wl[4][8192];   // W2s, W2t (natural), W3s, W3t (permuted)

  const int tid = threadIdx.x;
  const int lane = tid & 63, lg = lane >> 4, lm = lane & 15, wv = tid >> 6;
  const int sBase = (int)blockIdx.x * 128 + wv * 32;
  const bool owner = (lane < 32);

  float2 ab = make_float2(0.f, 0.f);
  if(owner) ab = ((const float2*)x)[sBase + lane];
  float* scat = out + 2 * BATCH;

#pragma unroll 1
  for(int i = 0; i < LNUM; ++i){
    const int parity = i & 1;
    const int off = i * WD, offW = i * (WD * WD);

    __syncthreads();
    stage_Wnat (sW2 + offW, Wl[0], tid);
    stage_Wnat (tW2 + offW, Wl[1], tid);
    stage_Wperm(sW3 + offW, Wl[2], tid);
    stage_Wperm(tW3 + offW, Wl[3], tid);
    __syncthreads();

    const float u = parity ? ab.y : ab.x;
    const float us0 = __shfl(u, lm, 64);
    const float us1 = __shfl(u, 16 + lm, 64);

    bf16x8 bvs[4][2], bvt[4][2];
    f32x4 as0[4][2], as1[4][2], at0[4][2], at1[4][2];
    TrQ tqs, tqt;
    pack_bv(us0, us1, sW1 + off, sb1 + off, lg, bvs);
    mid1_jb(Wl[0], sb2 + off, bvs, 0, lm, lg, as0);
    pack_bv(us0, us1, tW1 + off, tb1 + off, lg, bvt);
    mid1_jb(Wl[0], sb2 + off, bvs, 1, lm, lg, as1);
    mid1_jb(Wl[1], tb2 + off, bvt, 0, lm, lg, at0);
    trans_jb(as0, 0, tqs); trans_jb(as1, 1, tqs);
    mid1_jb(Wl[1], tb2 + off, bvt, 1, lm, lg, at1);
    trans_jb(at0, 0, tqt); trans_jb(at1, 1, tqt);

    f32x4 aas[2][2], aat[2][2];
    float ps0 = 0.f, ps1 = 0.f, pt0 = 0.f, pt1 = 0.f;
#pragma unroll
    for(int jt = 0; jt < 8; ++jt){
      MID2_STEP(Wl[2], sb3 + off, sW4 + off, tqs, aas, ps0, ps1, jt);
      MID2_STEP(Wl[3], tb3 + off, tW4 + off, tqt, aat, pt0, pt1, jt);
    }
    FOLDX(aas, ps0, ps1, sW4 + off, 7);
    FOLDX(aat, pt0, pt1, tW4 + off, 7);

    ps0 += __shfl_xor(ps0, 16, 64); ps0 += __shfl_xor(ps0, 32, 64);
    ps1 += __shfl_xor(ps1, 16, 64); ps1 += __shfl_xor(ps1, 32, 64);
    pt0 += __shfl_xor(pt0, 16, 64); pt0 += __shfl_xor(pt0, 32, 64);
    pt1 += __shfl_xor(pt1, 16, 64); pt1 += __shfl_xor(pt1, 32, 64);
    const float pres = ((lane & 16) ? ps1 : ps0) + sb4[i];
    const float pret = ((lane & 16) ? pt1 : pt0) + tb4[i];
    const float sv = s_scale[i] * tanhf(pres);
    const float tv = tanhf(pret);
    if(owner) scat[i * BATCH + sBase + lane] = sv;
    const float e = expf(sv);
    if(parity) ab.x = e * ab.x + tv; else ab.y = e * ab.y + tv;
  }

  if(owner) ((float2*)out)[sBase + lane] = ab;
}

extern "C" void kernel_launch(void* const* d_in, const int* in_sizes, int n_in,
                              void* d_out, int out_size, void* d_ws, size_t ws_size,
                              hipStream_t stream) {
  (void)in_sizes; (void)n_in; (void)out_size;
  const float* p[18];
  for(int k = 0; k < 18; ++k) p[k] = (const float*)d_in[k];

  const size_t need = (size_t)32 * 8192 * 4;   // 1 MiB bf16 weight image
  if(ws_size >= need){
    u32* ws = (u32*)d_ws;
    hipLaunchKernelGGL(prep_kernel, dim3(32), dim3(256), 0, stream,
                       p[4], p[6], p[12], p[14], ws);
    hipLaunchKernelGGL(flow_dma, dim3(BATCH / 256), dim3(512), 0, stream,
                       p[0], p[1], p[2], p[3], p[5], p[7], p[8], p[9],
                       p[10], p[11], p[13], p[15], p[16], p[17],
                       (const u32*)ws, (float*)d_out);
  } else {
    hipLaunchKernelGGL(flow_fb, dim3(BATCH / 128), dim3(256), 0, stream,
                       p[0], p[1], p[2], p[3], p[4], p[5], p[6], p[7], p[8], p[9],
                       p[10], p[11], p[12], p[13], p[14], p[15], p[16], p[17],
                       (float*)d_out);
  }
}